// Round 6
// baseline (337.037 us; speedup 1.0000x reference)
//
#include <hip/hip_runtime.h>

#define TT 6
#define D 128
#define KTOT 896           // 6*128 means + 128 x-slab
#define BM 128
#define SCAN_BLK 2048
#define LN_EPS 1e-5f

typedef __bf16 bf16x8 __attribute__((ext_vector_type(8)));
typedef float f32x4 __attribute__((ext_vector_type(4)));

__device__ __forceinline__ unsigned short f2bf(float f) {
    unsigned int u = __float_as_uint(f);
    unsigned int r = (u + 0x7FFFu + ((u >> 16) & 1u)) >> 16;  // RNE
    return (unsigned short)r;
}
__device__ __forceinline__ float bflo(unsigned int v) { return __uint_as_float(v << 16); }
__device__ __forceinline__ float bfhi(unsigned int v) { return __uint_as_float(v & 0xffff0000u); }

// XOR-swizzled LDS offset (ushort elems) for 128-elem rows: 16 chunks of 8.
__device__ __forceinline__ int lds_off128(int row, int kgrp) {
    return row * 128 + (((kgrp & 7) ^ (row & 7)) | (kgrp & 8)) * 8;
}

// --- setup: cast x->xb, transpose weights to bf16 WlT, bias_total, zero hist+flags ---
__global__ void setup_kernel(const float* __restrict__ x, const float* __restrict__ W_l,
                             const float* __restrict__ W_r, const float* __restrict__ b,
                             const float* __restrict__ emb,
                             unsigned short* __restrict__ xb, unsigned short* __restrict__ WlT,
                             float* __restrict__ bias_total, int* __restrict__ hist,
                             int* __restrict__ flag, int total8, int S, int NB) {
    int i = blockIdx.x * 256 + threadIdx.x;
    if (i < total8) {
        const float4* p = (const float4*)x + (size_t)i * 2;
        float4 a = p[0], bb = p[1];
        uint4 o;
        o.x = (unsigned int)f2bf(a.x) | ((unsigned int)f2bf(a.y) << 16);
        o.y = (unsigned int)f2bf(a.z) | ((unsigned int)f2bf(a.w) << 16);
        o.z = (unsigned int)f2bf(bb.x) | ((unsigned int)f2bf(bb.y) << 16);
        o.w = (unsigned int)f2bf(bb.z) | ((unsigned int)f2bf(bb.w) << 16);
        ((uint4*)xb)[i] = o;
        return;
    }
    i -= total8;
    if (i < 6 * D * D) {
        int t = i >> 14, rem = i & 16383, k = rem >> 7, n = rem & 127;
        WlT[n * KTOT + t * D + k] = f2bf(W_l[i]);
        return;
    }
    if (i < 7 * D * D) {
        int rem = i & 16383, k = rem >> 7, n = rem & 127;
        float s = 0.f;
#pragma unroll
        for (int tt = 0; tt < TT; ++tt) s += W_r[tt * D * D + rem];
        WlT[n * KTOT + TT * D + k] = f2bf(s);
        return;
    }
    if (i < 7 * D * D + D) {
        int o = i - 7 * D * D;
        float s = 0.f;
#pragma unroll
        for (int t = 0; t < TT; ++t) s += b[t * D + o] + emb[t * D + o];
        bias_total[o] = s;
        return;
    }
    i -= 7 * D * D + D;
    if (i < S) { hist[i] = 0; return; }
    i -= S;
    if (i < NB) flag[i] = 0;
}

// --- histogram of seg = t*N + dst (slab-contiguous CSR) ---
__global__ void hist_kernel(const int* __restrict__ ei, const int* __restrict__ et,
                            int* __restrict__ hist, int E, int N) {
    int e = blockIdx.x * 256 + threadIdx.x;
    if (e >= E) return;
    atomicAdd(&hist[et[e] * N + ei[E + e]], 1);
}

// --- single-dispatch exclusive scan (decoupled lookback, all-aggregate form).
//     147 blocks co-resident on 256 CUs: publish aggregate, then sum predecessors.
__global__ void scan_kernel(const int* __restrict__ in, int* __restrict__ off,
                            int* __restrict__ cursor, int* __restrict__ agg,
                            int* __restrict__ flag, int S, int E) {
    __shared__ int wsum[4];
    __shared__ int woff[4];
    __shared__ int psum[4];
    __shared__ int s_prefix;
    int tid = threadIdx.x;
    int tile = blockIdx.x;
    int base = tile * SCAN_BLK + tid * 8;
    int v[8];
    int ts = 0;
#pragma unroll
    for (int j = 0; j < 8; ++j) {
        v[j] = (base + j < S) ? in[base + j] : 0;
        ts += v[j];
    }
    int lane = tid & 63, wave = tid >> 6;
    int inc = ts;
#pragma unroll
    for (int o = 1; o < 64; o <<= 1) {
        int n = __shfl_up(inc, o);
        if (lane >= o) inc += n;
    }
    if (lane == 63) wsum[wave] = inc;
    __syncthreads();
    if (tid == 0) {
        int r = 0;
#pragma unroll
        for (int w = 0; w < 4; ++w) { int t = wsum[w]; woff[w] = r; r += t; }
        agg[tile] = r;
        __threadfence();
        atomicExch(&flag[tile], 1);
    }
    // lookback: each thread polls a subset of predecessor tiles
    int part = 0;
    for (int j = tid; j < tile; j += 256) {
        while (atomicAdd(&flag[j], 0) == 0) {}
        part += atomicAdd(&agg[j], 0);
    }
#pragma unroll
    for (int o = 32; o >= 1; o >>= 1) part += __shfl_down(part, o);
    if (lane == 0) psum[wave] = part;
    __syncthreads();
    if (tid == 0) s_prefix = psum[0] + psum[1] + psum[2] + psum[3];
    __syncthreads();
    int run = s_prefix + woff[wave] + inc - ts;
#pragma unroll
    for (int j = 0; j < 8; ++j) {
        if (base + j < S) { off[base + j] = run; cursor[base + j] = run; }
        run += v[j];
    }
    if (tile == 0 && tid == 0) off[S] = E;
}

__global__ void fill_kernel(const int* __restrict__ ei, const int* __restrict__ et,
                            int* __restrict__ cursor, int* __restrict__ sorted_src,
                            int E, int N) {
    int e = blockIdx.x * 256 + threadIdx.x;
    if (e >= E) return;
    int seg = et[e] * N + ei[E + e];
    int pos = atomicAdd(&cursor[seg], 1);
    sorted_src[pos] = ei[e];
}

// --- fused: ILP-8 mean aggregation -> bf16 MFMA over 7 K-slabs -> bias+LN+ReLU ---
__launch_bounds__(256, 2)
__global__ void fused_kernel(const unsigned short* __restrict__ xb,
                             const int* __restrict__ off, const int* __restrict__ sorted_src,
                             const unsigned short* __restrict__ WlT,
                             const float* __restrict__ bias_total,
                             const float* __restrict__ gamma, const float* __restrict__ beta,
                             float* __restrict__ out, int N) {
    __shared__ unsigned short As[BM * 128];   // 32 KB swizzled A slab [m][k]
    __shared__ unsigned short Bs[D * 128];    // 32 KB swizzled B slab [n][k]

    int tid = threadIdx.x;
    int lane = tid & 63, wave = tid >> 6;
    int q = lane >> 4, c16 = lane & 15;
    int qid = tid >> 4, l16 = tid & 15;       // 16 quarters x 16 lanes
    int blockRow = blockIdx.x * BM;

    f32x4 acc[2][8];
#pragma unroll
    for (int rt = 0; rt < 2; ++rt)
#pragma unroll
        for (int ct = 0; ct < 8; ++ct) acc[rt][ct] = (f32x4){0.f, 0.f, 0.f, 0.f};

#pragma unroll 1
    for (int t = 0; t < 7; ++t) {
        // B-slab global loads issued early (L2-hot)
        uint4 b_reg[8];
#pragma unroll
        for (int j = 0; j < 8; ++j) {
            int idx = j * 256 + tid, row = idx >> 4, kg = idx & 15;
            b_reg[j] = *(const uint4*)(WlT + (size_t)row * KTOT + t * D + kg * 8);
        }

        __syncthreads();   // previous MFMA frag reads complete

        if (t < TT) {
            // 8 independent segment accumulators per quarter-wave (MLP!)
            int e0[8], cn[8];
            int mx = 0;
#pragma unroll
            for (int i = 0; i < 8; ++i) {
                int node = blockRow + qid * 8 + i;
                if (node < N) {
                    int seg = t * N + node;
                    int a = off[seg], bnd = off[seg + 1];
                    e0[i] = a; cn[i] = bnd - a;
                } else { e0[i] = 0; cn[i] = 0; }
                mx = max(mx, cn[i]);
            }
            float ac[8][8];
#pragma unroll
            for (int i = 0; i < 8; ++i)
#pragma unroll
                for (int k = 0; k < 8; ++k) ac[i][k] = 0.f;

            for (int j = 0; j < mx; ++j) {
#pragma unroll
                for (int i = 0; i < 8; ++i) {
                    if (j < cn[i]) {
                        int s0 = sorted_src[e0[i] + j];
                        uint4 v = *(const uint4*)(xb + (size_t)s0 * D + l16 * 8);
                        ac[i][0] += bflo(v.x); ac[i][1] += bfhi(v.x);
                        ac[i][2] += bflo(v.y); ac[i][3] += bfhi(v.y);
                        ac[i][4] += bflo(v.z); ac[i][5] += bfhi(v.z);
                        ac[i][6] += bflo(v.w); ac[i][7] += bfhi(v.w);
                    }
                }
            }
#pragma unroll
            for (int i = 0; i < 8; ++i) {
                int row = qid * 8 + i;
                if (cn[i] > 1) {
                    float sc = 1.f / (float)cn[i];
#pragma unroll
                    for (int k = 0; k < 8; ++k) ac[i][k] *= sc;
                }
                uint4 p;
                p.x = (unsigned int)f2bf(ac[i][0]) | ((unsigned int)f2bf(ac[i][1]) << 16);
                p.y = (unsigned int)f2bf(ac[i][2]) | ((unsigned int)f2bf(ac[i][3]) << 16);
                p.z = (unsigned int)f2bf(ac[i][4]) | ((unsigned int)f2bf(ac[i][5]) << 16);
                p.w = (unsigned int)f2bf(ac[i][6]) | ((unsigned int)f2bf(ac[i][7]) << 16);
                *(uint4*)&As[lds_off128(row, l16)] = p;
            }
        } else {
            // x-slab: direct bf16 copy of this block's rows
#pragma unroll
            for (int j = 0; j < 8; ++j) {
                int idx = j * 256 + tid, row = idx >> 4, kg = idx & 15;
                int gr = blockRow + row;
                if (gr >= N) gr = N - 1;
                uint4 v = *(const uint4*)(xb + (size_t)gr * D + kg * 8);
                *(uint4*)&As[lds_off128(row, kg)] = v;
            }
        }

        // stage B slab
#pragma unroll
        for (int j = 0; j < 8; ++j) {
            int idx = j * 256 + tid, row = idx >> 4, kg = idx & 15;
            *(uint4*)&Bs[lds_off128(row, kg)] = b_reg[j];
        }
        __syncthreads();

        // MFMA: K=128 in 4 steps of 32
#pragma unroll
        for (int ks = 0; ks < 4; ++ks) {
            int kgrp = ks * 4 + q;
            bf16x8 af0 = *(const bf16x8*)&As[lds_off128(wave * 32 + c16, kgrp)];
            bf16x8 af1 = *(const bf16x8*)&As[lds_off128(wave * 32 + 16 + c16, kgrp)];
#pragma unroll
            for (int ct = 0; ct < 8; ++ct) {
                bf16x8 bfr = *(const bf16x8*)&Bs[lds_off128(ct * 16 + c16, kgrp)];
                acc[0][ct] = __builtin_amdgcn_mfma_f32_16x16x32_bf16(af0, bfr, acc[0][ct], 0, 0, 0);
                acc[1][ct] = __builtin_amdgcn_mfma_f32_16x16x32_bf16(af1, bfr, acc[1][ct], 0, 0, 0);
            }
        }
    }

    // epilogue: bias + LayerNorm + ReLU
    float bias_c[8], g_c[8], bt_c[8];
#pragma unroll
    for (int ct = 0; ct < 8; ++ct) {
        int col = ct * 16 + c16;
        bias_c[ct] = bias_total[col];
        g_c[ct] = gamma[col];
        bt_c[ct] = beta[col];
    }
#pragma unroll
    for (int rt = 0; rt < 2; ++rt) {
#pragma unroll
        for (int reg = 0; reg < 4; ++reg) {
            float h[8];
            float s = 0.f, s2 = 0.f;
#pragma unroll
            for (int ct = 0; ct < 8; ++ct) {
                h[ct] = acc[rt][ct][reg] + bias_c[ct];
                s += h[ct];
                s2 += h[ct] * h[ct];
            }
#pragma unroll
            for (int o = 8; o >= 1; o >>= 1) {
                s  += __shfl_xor(s, o, 16);
                s2 += __shfl_xor(s2, o, 16);
            }
            float mu = s * (1.f / 128.f);
            float var = s2 * (1.f / 128.f) - mu * mu;
            float rstd = rsqrtf(var + LN_EPS);
            int row = blockRow + wave * 32 + rt * 16 + q * 4 + reg;
            if (row < N) {
#pragma unroll
                for (int ct = 0; ct < 8; ++ct) {
                    float y = (h[ct] - mu) * rstd * g_c[ct] + bt_c[ct];
                    out[(size_t)row * D + ct * 16 + c16] = fmaxf(y, 0.f);
                }
            }
        }
    }
}

extern "C" void kernel_launch(void* const* d_in, const int* in_sizes, int n_in,
                              void* d_out, int out_size, void* d_ws, size_t ws_size,
                              hipStream_t stream) {
    const float* x     = (const float*)d_in[0];
    const int*   ei    = (const int*)d_in[1];
    const int*   et    = (const int*)d_in[2];
    const float* W_l   = (const float*)d_in[3];
    const float* W_r   = (const float*)d_in[4];
    const float* b     = (const float*)d_in[5];
    const float* emb   = (const float*)d_in[6];
    const float* gamma = (const float*)d_in[7];
    const float* beta  = (const float*)d_in[8];

    int N = in_sizes[0] / D;
    int E = in_sizes[2];
    int S = N * TT;
    int NB = (S + SCAN_BLK - 1) / SCAN_BLK;
    int NBLK = (N + BM - 1) / BM;

    // workspace carve
    int* hist       = (int*)d_ws;            // S
    int* off        = hist + S;              // S+1
    int* cursor     = off + S + 1;           // S
    int* agg        = cursor + S;            // NB
    int* flag       = agg + NB;              // NB
    int* sorted_src = flag + NB;             // E
    size_t ofs = (size_t)((char*)(sorted_src + E) - (char*)d_ws);
    ofs = (ofs + 15) & ~(size_t)15;
    unsigned short* WlT = (unsigned short*)((char*)d_ws + ofs);   // 128*896
    float* bias_total = (float*)(WlT + D * KTOT);                 // 128
    size_t ofs2 = (size_t)((char*)(bias_total + D) - (char*)d_ws);
    ofs2 = (ofs2 + 15) & ~(size_t)15;
    unsigned short* xb = (unsigned short*)((char*)d_ws + ofs2);   // N*128 bf16

    int total8 = N * D / 8;
    int G = total8 + 7 * D * D + D + S + NB;
    setup_kernel<<<(G + 255) / 256, 256, 0, stream>>>(x, W_l, W_r, b, emb, xb, WlT,
                                                      bias_total, hist, flag, total8, S, NB);

    hist_kernel<<<(E + 255) / 256, 256, 0, stream>>>(ei, et, hist, E, N);
    scan_kernel<<<NB, 256, 0, stream>>>(hist, off, cursor, agg, flag, S, E);
    fill_kernel<<<(E + 255) / 256, 256, 0, stream>>>(ei, et, cursor, sorted_src, E, N);

    fused_kernel<<<NBLK, 256, 0, stream>>>(xb, off, sorted_src, WlT, bias_total,
                                           gamma, beta, (float*)d_out, N);
}

// Round 7
// 281.010 us; speedup vs baseline: 1.1994x; 1.1994x over previous
//
#include <hip/hip_runtime.h>

#define TT 6
#define D 128
#define KTOT 896           // 6*128 means + 128 x-slab
#define BM 128
#define SCAN_BLK 2048
#define LN_EPS 1e-5f

typedef __bf16 bf16x8 __attribute__((ext_vector_type(8)));
typedef float f32x4 __attribute__((ext_vector_type(4)));

__device__ __forceinline__ unsigned short f2bf(float f) {
    unsigned int u = __float_as_uint(f);
    unsigned int r = (u + 0x7FFFu + ((u >> 16) & 1u)) >> 16;  // RNE
    return (unsigned short)r;
}
__device__ __forceinline__ float bflo(unsigned int v) { return __uint_as_float(v << 16); }
__device__ __forceinline__ float bfhi(unsigned int v) { return __uint_as_float(v & 0xffff0000u); }

// XOR-swizzled LDS offset (ushort elems) for 128-elem rows: 16 chunks of 8.
__device__ __forceinline__ int lds_off128(int row, int kgrp) {
    return row * 128 + (((kgrp & 7) ^ (row & 7)) | (kgrp & 8)) * 8;
}

// --- setup: cast x->xb, transpose weights to bf16 WlT, bias_total, zero hist+flags ---
__global__ void setup_kernel(const float* __restrict__ x, const float* __restrict__ W_l,
                             const float* __restrict__ W_r, const float* __restrict__ b,
                             const float* __restrict__ emb,
                             unsigned short* __restrict__ xb, unsigned short* __restrict__ WlT,
                             float* __restrict__ bias_total, int* __restrict__ hist,
                             int* __restrict__ flag, int total8, int S, int NB) {
    int i = blockIdx.x * 256 + threadIdx.x;
    if (i < total8) {
        const float4* p = (const float4*)x + (size_t)i * 2;
        float4 a = p[0], bb = p[1];
        uint4 o;
        o.x = (unsigned int)f2bf(a.x) | ((unsigned int)f2bf(a.y) << 16);
        o.y = (unsigned int)f2bf(a.z) | ((unsigned int)f2bf(a.w) << 16);
        o.z = (unsigned int)f2bf(bb.x) | ((unsigned int)f2bf(bb.y) << 16);
        o.w = (unsigned int)f2bf(bb.z) | ((unsigned int)f2bf(bb.w) << 16);
        ((uint4*)xb)[i] = o;
        return;
    }
    i -= total8;
    if (i < 6 * D * D) {
        int t = i >> 14, rem = i & 16383, k = rem >> 7, n = rem & 127;
        WlT[n * KTOT + t * D + k] = f2bf(W_l[i]);
        return;
    }
    if (i < 7 * D * D) {
        int rem = i & 16383, k = rem >> 7, n = rem & 127;
        float s = 0.f;
#pragma unroll
        for (int tt = 0; tt < TT; ++tt) s += W_r[tt * D * D + rem];
        WlT[n * KTOT + TT * D + k] = f2bf(s);
        return;
    }
    if (i < 7 * D * D + D) {
        int o = i - 7 * D * D;
        float s = 0.f;
#pragma unroll
        for (int t = 0; t < TT; ++t) s += b[t * D + o] + emb[t * D + o];
        bias_total[o] = s;
        return;
    }
    i -= 7 * D * D + D;
    if (i < S) { hist[i] = 0; return; }
    i -= S;
    if (i < NB) flag[i] = 0;
}

// --- histogram of seg = t*N + dst (slab-contiguous CSR) ---
__global__ void hist_kernel(const int* __restrict__ ei, const int* __restrict__ et,
                            int* __restrict__ hist, int E, int N) {
    int e = blockIdx.x * 256 + threadIdx.x;
    if (e >= E) return;
    atomicAdd(&hist[et[e] * N + ei[E + e]], 1);
}

// --- single-dispatch exclusive scan (decoupled lookback, all-aggregate form) ---
__global__ void scan_kernel(const int* __restrict__ in, int* __restrict__ off,
                            int* __restrict__ cursor, int* __restrict__ agg,
                            int* __restrict__ flag, int S, int E) {
    __shared__ int wsum[4];
    __shared__ int woff[4];
    __shared__ int psum[4];
    __shared__ int s_prefix;
    int tid = threadIdx.x;
    int tile = blockIdx.x;
    int base = tile * SCAN_BLK + tid * 8;
    int v[8];
    int ts = 0;
#pragma unroll
    for (int j = 0; j < 8; ++j) {
        v[j] = (base + j < S) ? in[base + j] : 0;
        ts += v[j];
    }
    int lane = tid & 63, wave = tid >> 6;
    int inc = ts;
#pragma unroll
    for (int o = 1; o < 64; o <<= 1) {
        int n = __shfl_up(inc, o);
        if (lane >= o) inc += n;
    }
    if (lane == 63) wsum[wave] = inc;
    __syncthreads();
    if (tid == 0) {
        int r = 0;
#pragma unroll
        for (int w = 0; w < 4; ++w) { int t = wsum[w]; woff[w] = r; r += t; }
        agg[tile] = r;
        __threadfence();
        atomicExch(&flag[tile], 1);
    }
    int part = 0;
    for (int j = tid; j < tile; j += 256) {
        while (atomicAdd(&flag[j], 0) == 0) {}
        part += atomicAdd(&agg[j], 0);
    }
#pragma unroll
    for (int o = 32; o >= 1; o >>= 1) part += __shfl_down(part, o);
    if (lane == 0) psum[wave] = part;
    __syncthreads();
    if (tid == 0) s_prefix = psum[0] + psum[1] + psum[2] + psum[3];
    __syncthreads();
    int run = s_prefix + woff[wave] + inc - ts;
#pragma unroll
    for (int j = 0; j < 8; ++j) {
        if (base + j < S) { off[base + j] = run; cursor[base + j] = run; }
        run += v[j];
    }
    if (tile == 0 && tid == 0) off[S] = E;
}

__global__ void fill_kernel(const int* __restrict__ ei, const int* __restrict__ et,
                            int* __restrict__ cursor, int* __restrict__ sorted_src,
                            int E, int N) {
    int e = blockIdx.x * 256 + threadIdx.x;
    if (e >= E) return;
    int seg = et[e] * N + ei[E + e];
    int pos = atomicAdd(&cursor[seg], 1);
    sorted_src[pos] = ei[e];
}

// --- fused: prefetch-2 pipelined mean aggregation -> bf16 MFMA -> bias+LN+ReLU ---
__launch_bounds__(256, 2)
__global__ void fused_kernel(const unsigned short* __restrict__ xb,
                             const int* __restrict__ off, const int* __restrict__ sorted_src,
                             const unsigned short* __restrict__ WlT,
                             const float* __restrict__ bias_total,
                             const float* __restrict__ gamma, const float* __restrict__ beta,
                             float* __restrict__ out, int N) {
    __shared__ unsigned short As[BM * 128];   // 32 KB swizzled A slab [m][k]
    __shared__ unsigned short Bs[D * 128];    // 32 KB swizzled B slab [n][k]
    __shared__ int offs[TT * 129];            // block's CSR bounds, all slabs

    int tid = threadIdx.x;
    int lane = tid & 63, wave = tid >> 6;
    int q = lane >> 4, c16 = lane & 15;
    int qid = tid >> 4, l16 = tid & 15;       // 16 quarters x 16 lanes
    int blockRow = blockIdx.x * BM;

    // preload CSR bounds: slab t needs off[t*N + blockRow .. +128]
    for (int i = tid; i < TT * 129; i += 256) {
        int t = i / 129, r = i - t * 129;
        int g = blockRow + r; if (g > N) g = N;
        offs[i] = off[t * N + g];
    }

    f32x4 acc[2][8];
#pragma unroll
    for (int rt = 0; rt < 2; ++rt)
#pragma unroll
        for (int ct = 0; ct < 8; ++ct) acc[rt][ct] = (f32x4){0.f, 0.f, 0.f, 0.f};

    __syncthreads();   // offs ready

#pragma unroll 1
    for (int t = 0; t < 7; ++t) {
        // B-slab global loads issued early (L2-hot broadcast)
        uint4 b_reg[8];
#pragma unroll
        for (int j = 0; j < 8; ++j) {
            int idx = j * 256 + tid, row = idx >> 4, kg = idx & 15;
            b_reg[j] = *(const uint4*)(WlT + (size_t)row * KTOT + t * D + kg * 8);
        }

        __syncthreads();   // previous MFMA frag reads complete

        if (t < TT) {
            int rowbase = qid * 8;
            // stage 1: bounds for 8 rows
            int e0[8], cn[8];
#pragma unroll
            for (int i = 0; i < 8; ++i) {
                int row = rowbase + i;
                int a = offs[t * 129 + row];
                int bnd = offs[t * 129 + row + 1];
                e0[i] = a;
                cn[i] = (blockRow + row < N) ? (bnd - a) : 0;
            }
            // stage 2: prefetch first-2 edge indices of every row (16 independent loads)
            int i0[8], i1[8];
#pragma unroll
            for (int i = 0; i < 8; ++i) {
                i0[i] = 0; i1[i] = 0;
                if (cn[i] > 0) i0[i] = sorted_src[e0[i]];
                if (cn[i] > 1) i1[i] = sorted_src[e0[i] + 1];
            }
            // stage 3: issue all first-2 gathers (16 outstanding 16B loads)
            uint4 v0[8], v1[8];
#pragma unroll
            for (int i = 0; i < 8; ++i) {
                v0[i] = (uint4){0u, 0u, 0u, 0u};
                if (cn[i] > 0) v0[i] = *(const uint4*)(xb + (size_t)i0[i] * D + l16 * 8);
            }
#pragma unroll
            for (int i = 0; i < 8; ++i) {
                v1[i] = (uint4){0u, 0u, 0u, 0u};
                if (cn[i] > 1) v1[i] = *(const uint4*)(xb + (size_t)i1[i] * D + l16 * 8);
            }
            // stage 4: drain, serial tail for cnt>2 (~30% rows), scale, pack, store
#pragma unroll
            for (int i = 0; i < 8; ++i) {
                float a0 = bflo(v0[i].x) + bflo(v1[i].x);
                float a1 = bfhi(v0[i].x) + bfhi(v1[i].x);
                float a2 = bflo(v0[i].y) + bflo(v1[i].y);
                float a3 = bfhi(v0[i].y) + bfhi(v1[i].y);
                float a4 = bflo(v0[i].z) + bflo(v1[i].z);
                float a5 = bfhi(v0[i].z) + bfhi(v1[i].z);
                float a6 = bflo(v0[i].w) + bflo(v1[i].w);
                float a7 = bfhi(v0[i].w) + bfhi(v1[i].w);
                int e = e0[i] + 2, end = e0[i] + cn[i];
#pragma unroll 1
                while (e < end) {
                    int s = sorted_src[e++];
                    uint4 v = *(const uint4*)(xb + (size_t)s * D + l16 * 8);
                    a0 += bflo(v.x); a1 += bfhi(v.x);
                    a2 += bflo(v.y); a3 += bfhi(v.y);
                    a4 += bflo(v.z); a5 += bfhi(v.z);
                    a6 += bflo(v.w); a7 += bfhi(v.w);
                }
                if (cn[i] > 1) {
                    float sc = 1.f / (float)cn[i];
                    a0 *= sc; a1 *= sc; a2 *= sc; a3 *= sc;
                    a4 *= sc; a5 *= sc; a6 *= sc; a7 *= sc;
                }
                uint4 p;
                p.x = (unsigned int)f2bf(a0) | ((unsigned int)f2bf(a1) << 16);
                p.y = (unsigned int)f2bf(a2) | ((unsigned int)f2bf(a3) << 16);
                p.z = (unsigned int)f2bf(a4) | ((unsigned int)f2bf(a5) << 16);
                p.w = (unsigned int)f2bf(a6) | ((unsigned int)f2bf(a7) << 16);
                *(uint4*)&As[lds_off128(rowbase + i, l16)] = p;
            }
        } else {
            // x-slab: direct bf16 copy of this block's rows
#pragma unroll
            for (int j = 0; j < 8; ++j) {
                int idx = j * 256 + tid, row = idx >> 4, kg = idx & 15;
                int gr = blockRow + row;
                if (gr >= N) gr = N - 1;
                uint4 v = *(const uint4*)(xb + (size_t)gr * D + kg * 8);
                *(uint4*)&As[lds_off128(row, kg)] = v;
            }
        }

        // stage B slab
#pragma unroll
        for (int j = 0; j < 8; ++j) {
            int idx = j * 256 + tid, row = idx >> 4, kg = idx & 15;
            *(uint4*)&Bs[lds_off128(row, kg)] = b_reg[j];
        }
        __syncthreads();

        // MFMA: K=128 in 4 steps of 32
#pragma unroll
        for (int ks = 0; ks < 4; ++ks) {
            int kgrp = ks * 4 + q;
            bf16x8 af0 = *(const bf16x8*)&As[lds_off128(wave * 32 + c16, kgrp)];
            bf16x8 af1 = *(const bf16x8*)&As[lds_off128(wave * 32 + 16 + c16, kgrp)];
#pragma unroll
            for (int ct = 0; ct < 8; ++ct) {
                bf16x8 bfr = *(const bf16x8*)&Bs[lds_off128(ct * 16 + c16, kgrp)];
                acc[0][ct] = __builtin_amdgcn_mfma_f32_16x16x32_bf16(af0, bfr, acc[0][ct], 0, 0, 0);
                acc[1][ct] = __builtin_amdgcn_mfma_f32_16x16x32_bf16(af1, bfr, acc[1][ct], 0, 0, 0);
            }
        }
    }

    // epilogue: bias + LayerNorm + ReLU
    float bias_c[8], g_c[8], bt_c[8];
#pragma unroll
    for (int ct = 0; ct < 8; ++ct) {
        int col = ct * 16 + c16;
        bias_c[ct] = bias_total[col];
        g_c[ct] = gamma[col];
        bt_c[ct] = beta[col];
    }
#pragma unroll
    for (int rt = 0; rt < 2; ++rt) {
#pragma unroll
        for (int reg = 0; reg < 4; ++reg) {
            float h[8];
            float s = 0.f, s2 = 0.f;
#pragma unroll
            for (int ct = 0; ct < 8; ++ct) {
                h[ct] = acc[rt][ct][reg] + bias_c[ct];
                s += h[ct];
                s2 += h[ct] * h[ct];
            }
#pragma unroll
            for (int o = 8; o >= 1; o >>= 1) {
                s  += __shfl_xor(s, o, 16);
                s2 += __shfl_xor(s2, o, 16);
            }
            float mu = s * (1.f / 128.f);
            float var = s2 * (1.f / 128.f) - mu * mu;
            float rstd = rsqrtf(var + LN_EPS);
            int row = blockRow + wave * 32 + rt * 16 + q * 4 + reg;
            if (row < N) {
#pragma unroll
                for (int ct = 0; ct < 8; ++ct) {
                    float y = (h[ct] - mu) * rstd * g_c[ct] + bt_c[ct];
                    out[(size_t)row * D + ct * 16 + c16] = fmaxf(y, 0.f);
                }
            }
        }
    }
}

extern "C" void kernel_launch(void* const* d_in, const int* in_sizes, int n_in,
                              void* d_out, int out_size, void* d_ws, size_t ws_size,
                              hipStream_t stream) {
    const float* x     = (const float*)d_in[0];
    const int*   ei    = (const int*)d_in[1];
    const int*   et    = (const int*)d_in[2];
    const float* W_l   = (const float*)d_in[3];
    const float* W_r   = (const float*)d_in[4];
    const float* b     = (const float*)d_in[5];
    const float* emb   = (const float*)d_in[6];
    const float* gamma = (const float*)d_in[7];
    const float* beta  = (const float*)d_in[8];

    int N = in_sizes[0] / D;
    int E = in_sizes[2];
    int S = N * TT;
    int NB = (S + SCAN_BLK - 1) / SCAN_BLK;
    int NBLK = (N + BM - 1) / BM;

    // workspace carve
    int* hist       = (int*)d_ws;            // S
    int* off        = hist + S;              // S+1
    int* cursor     = off + S + 1;           // S
    int* agg        = cursor + S;            // NB
    int* flag       = agg + NB;              // NB
    int* sorted_src = flag + NB;             // E
    size_t ofs = (size_t)((char*)(sorted_src + E) - (char*)d_ws);
    ofs = (ofs + 15) & ~(size_t)15;
    unsigned short* WlT = (unsigned short*)((char*)d_ws + ofs);   // 128*896
    float* bias_total = (float*)(WlT + D * KTOT);                 // 128
    size_t ofs2 = (size_t)((char*)(bias_total + D) - (char*)d_ws);
    ofs2 = (ofs2 + 15) & ~(size_t)15;
    unsigned short* xb = (unsigned short*)((char*)d_ws + ofs2);   // N*128 bf16

    int total8 = N * D / 8;
    int G = total8 + 7 * D * D + D + S + NB;
    setup_kernel<<<(G + 255) / 256, 256, 0, stream>>>(x, W_l, W_r, b, emb, xb, WlT,
                                                      bias_total, hist, flag, total8, S, NB);

    hist_kernel<<<(E + 255) / 256, 256, 0, stream>>>(ei, et, hist, E, N);
    scan_kernel<<<NB, 256, 0, stream>>>(hist, off, cursor, agg, flag, S, E);
    fill_kernel<<<(E + 255) / 256, 256, 0, stream>>>(ei, et, cursor, sorted_src, E, N);

    fused_kernel<<<NBLK, 256, 0, stream>>>(xb, off, sorted_src, WlT, bias_total,
                                           gamma, beta, (float*)d_out, N);
}